// Round 7
// baseline (499.262 us; speedup 1.0000x reference)
//
#include <hip/hip_runtime.h>
#include <math.h>

constexpr int NN = 100000;   // nodes
constexpr int NE = 1600000;  // edges
constexpr int DI = 128;      // input dim
constexpr int DH = 128;      // hidden dim
constexpr int NC = 64;       // classes
constexpr int NB = (NN + 255) / 256;   // 391 scan blocks

// bf16 pack/unpack (RNE). Internal z1/z2 stored bf16 (halves gather bytes).
__device__ __forceinline__ unsigned short f2bf(float f) {
    const unsigned u = __float_as_uint(f);
    return (unsigned short)((u + 0x7FFFu + ((u >> 16) & 1u)) >> 16);
}
__device__ __forceinline__ float bf_lo(unsigned u) {
    return __uint_as_float(u << 16);
}
__device__ __forceinline__ float bf_hi(unsigned u) {
    return __uint_as_float(u & 0xFFFF0000u);
}

// ---------------------------------------------------------------------------
// Kernel 1: z1 = bf16(l2normalize(x) @ W1 + b1)  (round-5 structure, proven)
// ---------------------------------------------------------------------------
__global__ __launch_bounds__(512) void k_norm_gemm1(
    const float* __restrict__ x, const float* __restrict__ W1,
    const float* __restrict__ b1, unsigned short* __restrict__ z1h)
{
    __shared__ float4 sW4[64][64];   // 64 KB quad-paired
    __shared__ float sx[8][4][DI];   // 16 KB

    const int tid = threadIdx.x;
    for (int i = tid; i < 64 * 64; i += 512) {
        const int k2 = i >> 6, c = i & 63;
        const float* wp = W1 + (size_t)(2 * k2) * DH + c;
        sW4[k2][c] = make_float4(wp[0], wp[64], wp[DH], wp[DH + 64]);
    }
    __syncthreads();

    const int wave = tid >> 6, lane = tid & 63;
    const float bias0 = b1[lane];
    const float bias1 = b1[64 + lane];

    for (int base = (blockIdx.x * 8 + wave) * 4; base < NN;
         base += gridDim.x * 32) {
        #pragma unroll
        for (int r = 0; r < 4; ++r) {
            const int row = base + r;
            float a0 = 0.f, a1 = 0.f;
            if (row < NN) {
                a0 = x[(size_t)row * DI + lane];
                a1 = x[(size_t)row * DI + 64 + lane];
            }
            float ss = a0 * a0 + a1 * a1;
            #pragma unroll
            for (int off = 32; off; off >>= 1) ss += __shfl_xor(ss, off);
            const float rinv = 1.0f / fmaxf(sqrtf(ss), 1e-12f);
            sx[wave][r][lane]      = a0 * rinv;
            sx[wave][r][64 + lane] = a1 * rinv;
        }

        float acc[4][2];
        #pragma unroll
        for (int r = 0; r < 4; ++r) { acc[r][0] = bias0; acc[r][1] = bias1; }

        #pragma unroll 2
        for (int k2 = 0; k2 < 64; k2 += 2) {
            const float4 w0 = sW4[k2][lane];
            const float4 w1 = sW4[k2 + 1][lane];
            #pragma unroll
            for (int r = 0; r < 4; ++r) {
                const float4 xv = *(const float4*)(&sx[wave][r][2 * k2]);
                acc[r][0] = fmaf(xv.x, w0.x, acc[r][0]);
                acc[r][1] = fmaf(xv.x, w0.y, acc[r][1]);
                acc[r][0] = fmaf(xv.y, w0.z, acc[r][0]);
                acc[r][1] = fmaf(xv.y, w0.w, acc[r][1]);
                acc[r][0] = fmaf(xv.z, w1.x, acc[r][0]);
                acc[r][1] = fmaf(xv.z, w1.y, acc[r][1]);
                acc[r][0] = fmaf(xv.w, w1.z, acc[r][0]);
                acc[r][1] = fmaf(xv.w, w1.w, acc[r][1]);
            }
        }
        #pragma unroll
        for (int r = 0; r < 4; ++r) {
            const int row = base + r;
            if (row < NN) {
                z1h[(size_t)row * DH + lane]      = f2bf(acc[r][0]);
                z1h[(size_t)row * DH + 64 + lane] = f2bf(acc[r][1]);
            }
        }
    }
}

// ---------------------------------------------------------------------------
// CSR build: histogram -> 3-kernel exclusive scan -> (src,w) scatter
// ---------------------------------------------------------------------------
__global__ __launch_bounds__(256) void k_hist(
    const int* __restrict__ dst, int* __restrict__ cnt)
{
    for (int e = blockIdx.x * 256 + threadIdx.x; e < NE; e += gridDim.x * 256)
        atomicAdd(&cnt[dst[e]], 1);
}

__global__ __launch_bounds__(256) void k_scanA(
    const int* __restrict__ cnt, int* __restrict__ rowptr,
    int* __restrict__ bsum)
{
    __shared__ int tmp[256];
    const int t = threadIdx.x;
    const int gid = blockIdx.x * 256 + t;
    const int v = (gid < NN) ? cnt[gid] : 0;
    tmp[t] = v;
    __syncthreads();
    #pragma unroll
    for (int off = 1; off < 256; off <<= 1) {
        const int add = (t >= off) ? tmp[t - off] : 0;
        __syncthreads();
        tmp[t] += add;
        __syncthreads();
    }
    if (gid < NN) rowptr[gid] = tmp[t] - v;
    if (t == 255) bsum[blockIdx.x] = tmp[255];
}

__global__ __launch_bounds__(512) void k_scanB(int* __restrict__ bsum)
{
    __shared__ int tmp[512];
    const int t = threadIdx.x;
    const int v = (t < NB) ? bsum[t] : 0;
    tmp[t] = v;
    __syncthreads();
    #pragma unroll
    for (int off = 1; off < 512; off <<= 1) {
        const int add = (t >= off) ? tmp[t - off] : 0;
        __syncthreads();
        tmp[t] += add;
        __syncthreads();
    }
    if (t < NB) bsum[t] = tmp[t] - v;
}

__global__ __launch_bounds__(256) void k_scanC(
    int* __restrict__ rowptr, const int* __restrict__ bsum,
    int* __restrict__ offs)
{
    const int gid = blockIdx.x * 256 + threadIdx.x;
    if (gid < NN) {
        const int r = rowptr[gid] + bsum[blockIdx.x];
        rowptr[gid] = r;
        offs[gid]   = r;
    }
    if (gid == 0) rowptr[NN] = NE;
}

__global__ __launch_bounds__(256) void k_scatter(
    const int* __restrict__ src, const int* __restrict__ dst,
    const float* __restrict__ ew, int* __restrict__ offs,
    int2* __restrict__ srcw)
{
    for (int e = blockIdx.x * 256 + threadIdx.x; e < NE; e += gridDim.x * 256) {
        const int pos = atomicAdd(&offs[dst[e]], 1);
        srcw[pos] = make_int2(src[e], __float_as_int(ew[e]));
    }
}

// ---------------------------------------------------------------------------
// Fused: agg = relu(spmm(z1h)); z2 = bf16(agg @ W2 + b2)
// x8 edge unroll: 8 outstanding 256B row-gathers per wave (round-6 lesson:
// this kernel is L2-miss LATENCY bound; MLP, not bytes, is the lever).
// ---------------------------------------------------------------------------
__global__ __launch_bounds__(512) void k_spmm1_gemm2(
    const unsigned short* __restrict__ h, const int* __restrict__ rowptr,
    const int2* __restrict__ srcw, const float* __restrict__ W2,
    const float* __restrict__ b2, unsigned short* __restrict__ z2h)
{
    __shared__ float sW2[DH * NC];   // 32 KB
    __shared__ float sagg[8][DH];    // 4 KB

    const int tid = threadIdx.x;
    {
        const float4* W4 = (const float4*)W2;
        float4* s4 = (float4*)sW2;
        #pragma unroll
        for (int i = 0; i < DH * NC / 4 / 512; ++i)
            s4[tid + i * 512] = W4[tid + i * 512];
    }
    __syncthreads();

    const int wave = tid >> 6, lane = tid & 63;
    const float bias = b2[lane];
    const unsigned* hu = (const unsigned*)h;   // 64 uints per row

    for (int row = blockIdx.x * 8 + wave; row < NN; row += gridDim.x * 8) {
        const int start = rowptr[row], end = rowptr[row + 1];
        float acc0 = 0.f, acc1 = 0.f;   // dims 2*lane, 2*lane+1
        int e = start;
        for (; e + 8 <= end; e += 8) {
            const int2 s0 = srcw[e + 0], s1 = srcw[e + 1];
            const int2 s2 = srcw[e + 2], s3 = srcw[e + 3];
            const int2 s4 = srcw[e + 4], s5 = srcw[e + 5];
            const int2 s6 = srcw[e + 6], s7 = srcw[e + 7];
            const unsigned u0 = hu[(size_t)s0.x * 64 + lane];
            const unsigned u1 = hu[(size_t)s1.x * 64 + lane];
            const unsigned u2 = hu[(size_t)s2.x * 64 + lane];
            const unsigned u3 = hu[(size_t)s3.x * 64 + lane];
            const unsigned u4 = hu[(size_t)s4.x * 64 + lane];
            const unsigned u5 = hu[(size_t)s5.x * 64 + lane];
            const unsigned u6 = hu[(size_t)s6.x * 64 + lane];
            const unsigned u7 = hu[(size_t)s7.x * 64 + lane];
            acc0 = fmaf(__int_as_float(s0.y), bf_lo(u0), acc0);
            acc1 = fmaf(__int_as_float(s0.y), bf_hi(u0), acc1);
            acc0 = fmaf(__int_as_float(s1.y), bf_lo(u1), acc0);
            acc1 = fmaf(__int_as_float(s1.y), bf_hi(u1), acc1);
            acc0 = fmaf(__int_as_float(s2.y), bf_lo(u2), acc0);
            acc1 = fmaf(__int_as_float(s2.y), bf_hi(u2), acc1);
            acc0 = fmaf(__int_as_float(s3.y), bf_lo(u3), acc0);
            acc1 = fmaf(__int_as_float(s3.y), bf_hi(u3), acc1);
            acc0 = fmaf(__int_as_float(s4.y), bf_lo(u4), acc0);
            acc1 = fmaf(__int_as_float(s4.y), bf_hi(u4), acc1);
            acc0 = fmaf(__int_as_float(s5.y), bf_lo(u5), acc0);
            acc1 = fmaf(__int_as_float(s5.y), bf_hi(u5), acc1);
            acc0 = fmaf(__int_as_float(s6.y), bf_lo(u6), acc0);
            acc1 = fmaf(__int_as_float(s6.y), bf_hi(u6), acc1);
            acc0 = fmaf(__int_as_float(s7.y), bf_lo(u7), acc0);
            acc1 = fmaf(__int_as_float(s7.y), bf_hi(u7), acc1);
        }
        for (; e + 4 <= end; e += 4) {
            const int2 s0 = srcw[e + 0], s1 = srcw[e + 1];
            const int2 s2 = srcw[e + 2], s3 = srcw[e + 3];
            const unsigned u0 = hu[(size_t)s0.x * 64 + lane];
            const unsigned u1 = hu[(size_t)s1.x * 64 + lane];
            const unsigned u2 = hu[(size_t)s2.x * 64 + lane];
            const unsigned u3 = hu[(size_t)s3.x * 64 + lane];
            acc0 = fmaf(__int_as_float(s0.y), bf_lo(u0), acc0);
            acc1 = fmaf(__int_as_float(s0.y), bf_hi(u0), acc1);
            acc0 = fmaf(__int_as_float(s1.y), bf_lo(u1), acc0);
            acc1 = fmaf(__int_as_float(s1.y), bf_hi(u1), acc1);
            acc0 = fmaf(__int_as_float(s2.y), bf_lo(u2), acc0);
            acc1 = fmaf(__int_as_float(s2.y), bf_hi(u2), acc1);
            acc0 = fmaf(__int_as_float(s3.y), bf_lo(u3), acc0);
            acc1 = fmaf(__int_as_float(s3.y), bf_hi(u3), acc1);
        }
        for (; e < end; ++e) {
            const int2 s = srcw[e];
            const unsigned u = hu[(size_t)s.x * 64 + lane];
            acc0 = fmaf(__int_as_float(s.y), bf_lo(u), acc0);
            acc1 = fmaf(__int_as_float(s.y), bf_hi(u), acc1);
        }
        *(float2*)&sagg[wave][2 * lane] =
            make_float2(fmaxf(acc0, 0.f), fmaxf(acc1, 0.f));

        float acc = bias;
        #pragma unroll
        for (int k = 0; k < DH; k += 4) {
            float a4[4];
            *(float4*)a4 = *(const float4*)(&sagg[wave][k]);
            acc = fmaf(a4[0], sW2[(k + 0) * NC + lane], acc);
            acc = fmaf(a4[1], sW2[(k + 1) * NC + lane], acc);
            acc = fmaf(a4[2], sW2[(k + 2) * NC + lane], acc);
            acc = fmaf(a4[3], sW2[(k + 3) * NC + lane], acc);
        }
        z2h[(size_t)row * NC + lane] = f2bf(acc);
    }
}

// ---------------------------------------------------------------------------
// Gather-SPMM D=64 (bf16 table) + fused softmax, x8 edge unroll
// ---------------------------------------------------------------------------
__global__ __launch_bounds__(256) void k_spmm2_softmax(
    const unsigned short* __restrict__ z2h, const int* __restrict__ rowptr,
    const int2* __restrict__ srcw, float* __restrict__ out)
{
    const int row = blockIdx.x * 4 + (threadIdx.x >> 6);
    if (row >= NN) return;
    const int lane = threadIdx.x & 63;
    const int start = rowptr[row], end = rowptr[row + 1];
    float acc = 0.f;
    int e = start;
    for (; e + 8 <= end; e += 8) {
        const int2 s0 = srcw[e + 0], s1 = srcw[e + 1];
        const int2 s2 = srcw[e + 2], s3 = srcw[e + 3];
        const int2 s4 = srcw[e + 4], s5 = srcw[e + 5];
        const int2 s6 = srcw[e + 6], s7 = srcw[e + 7];
        const unsigned short t0 = z2h[(size_t)s0.x * NC + lane];
        const unsigned short t1 = z2h[(size_t)s1.x * NC + lane];
        const unsigned short t2 = z2h[(size_t)s2.x * NC + lane];
        const unsigned short t3 = z2h[(size_t)s3.x * NC + lane];
        const unsigned short t4 = z2h[(size_t)s4.x * NC + lane];
        const unsigned short t5 = z2h[(size_t)s5.x * NC + lane];
        const unsigned short t6 = z2h[(size_t)s6.x * NC + lane];
        const unsigned short t7 = z2h[(size_t)s7.x * NC + lane];
        acc = fmaf(__int_as_float(s0.y), __uint_as_float((unsigned)t0 << 16), acc);
        acc = fmaf(__int_as_float(s1.y), __uint_as_float((unsigned)t1 << 16), acc);
        acc = fmaf(__int_as_float(s2.y), __uint_as_float((unsigned)t2 << 16), acc);
        acc = fmaf(__int_as_float(s3.y), __uint_as_float((unsigned)t3 << 16), acc);
        acc = fmaf(__int_as_float(s4.y), __uint_as_float((unsigned)t4 << 16), acc);
        acc = fmaf(__int_as_float(s5.y), __uint_as_float((unsigned)t5 << 16), acc);
        acc = fmaf(__int_as_float(s6.y), __uint_as_float((unsigned)t6 << 16), acc);
        acc = fmaf(__int_as_float(s7.y), __uint_as_float((unsigned)t7 << 16), acc);
    }
    for (; e + 4 <= end; e += 4) {
        const int2 s0 = srcw[e + 0], s1 = srcw[e + 1];
        const int2 s2 = srcw[e + 2], s3 = srcw[e + 3];
        const unsigned short t0 = z2h[(size_t)s0.x * NC + lane];
        const unsigned short t1 = z2h[(size_t)s1.x * NC + lane];
        const unsigned short t2 = z2h[(size_t)s2.x * NC + lane];
        const unsigned short t3 = z2h[(size_t)s3.x * NC + lane];
        acc = fmaf(__int_as_float(s0.y), __uint_as_float((unsigned)t0 << 16), acc);
        acc = fmaf(__int_as_float(s1.y), __uint_as_float((unsigned)t1 << 16), acc);
        acc = fmaf(__int_as_float(s2.y), __uint_as_float((unsigned)t2 << 16), acc);
        acc = fmaf(__int_as_float(s3.y), __uint_as_float((unsigned)t3 << 16), acc);
    }
    for (; e < end; ++e) {
        const int2 s = srcw[e];
        const float v = __uint_as_float((unsigned)z2h[(size_t)s.x * NC + lane] << 16);
        acc = fmaf(__int_as_float(s.y), v, acc);
    }
    float m = acc;
    #pragma unroll
    for (int off = 32; off; off >>= 1) m = fmaxf(m, __shfl_xor(m, off));
    const float ex = __expf(acc - m);
    float s = ex;
    #pragma unroll
    for (int off = 32; off; off >>= 1) s += __shfl_xor(s, off);
    out[(size_t)row * NC + lane] = ex / s;
}

// ---------------------------------------------------------------------------
extern "C" void kernel_launch(void* const* d_in, const int* in_sizes, int n_in,
                              void* d_out, int out_size, void* d_ws,
                              size_t ws_size, hipStream_t stream)
{
    const float* x  = (const float*)d_in[0];
    const int* src  = (const int*)d_in[1];
    const int* dst  = (const int*)d_in[2];
    const float* ew = (const float*)d_in[3];
    const float* W1 = (const float*)d_in[4];
    const float* b1 = (const float*)d_in[5];
    const float* W2 = (const float*)d_in[6];
    const float* b2 = (const float*)d_in[7];
    float* out = (float*)d_out;

    char* base = (char*)d_ws;
    unsigned short* z1h = (unsigned short*)base;  base += (size_t)NN * DH * 2;
    unsigned short* z2h = (unsigned short*)base;  base += (size_t)NN * NC * 2;
    int2*  srcw = (int2*)base;                    base += (size_t)NE * 8;
    int* rowptr = (int*)base;                     base += ((size_t)NN + 2) * 4;
    int* offs   = (int*)base;                     base += (size_t)NN * 4;
    int* bsum   = (int*)base;                     base += 512 * 4;
    int* cnt    = offs;                           // cnt dead after scanA

    hipMemsetAsync(cnt, 0, (size_t)NN * 4, stream);

    k_norm_gemm1<<<1024, 512, 0, stream>>>(x, W1, b1, z1h);

    k_hist   <<<2048, 256, 0, stream>>>(dst, cnt);
    k_scanA  <<<NB, 256, 0, stream>>>(cnt, rowptr, bsum);
    k_scanB  <<<1, 512, 0, stream>>>(bsum);
    k_scanC  <<<NB, 256, 0, stream>>>(rowptr, bsum, offs);
    k_scatter<<<2048, 256, 0, stream>>>(src, dst, ew, offs, srcw);

    k_spmm1_gemm2   <<<2048, 512, 0, stream>>>(z1h, rowptr, srcw, W2, b2, z2h);
    k_spmm2_softmax <<<(NN + 3) / 4, 256, 0, stream>>>(z2h, rowptr, srcw, out);
}

// Round 8
// 401.668 us; speedup vs baseline: 1.2430x; 1.2430x over previous
//
#include <hip/hip_runtime.h>
#include <math.h>

constexpr int NN = 100000;   // nodes
constexpr int NE = 1600000;  // edges
constexpr int DI = 128;      // input dim
constexpr int DH = 128;      // hidden dim
constexpr int NC = 64;       // classes
constexpr int NB = (NN + 255) / 256;   // 391 scan blocks

// bf16 pack/unpack (RNE). Internal z1/z2 and W2 stored bf16.
__device__ __forceinline__ unsigned short f2bf(float f) {
    const unsigned u = __float_as_uint(f);
    return (unsigned short)((u + 0x7FFFu + ((u >> 16) & 1u)) >> 16);
}
__device__ __forceinline__ float bf_lo(unsigned u) {
    return __uint_as_float(u << 16);
}
__device__ __forceinline__ float bf_hi(unsigned u) {
    return __uint_as_float(u & 0xFFFF0000u);
}

// ---------------------------------------------------------------------------
// Kernel 1: z1 = bf16(l2normalize(x) @ W1 + b1)  (round-5 structure, proven)
// ---------------------------------------------------------------------------
__global__ __launch_bounds__(512) void k_norm_gemm1(
    const float* __restrict__ x, const float* __restrict__ W1,
    const float* __restrict__ b1, unsigned short* __restrict__ z1h)
{
    __shared__ float4 sW4[64][64];   // 64 KB quad-paired
    __shared__ float sx[8][4][DI];   // 16 KB

    const int tid = threadIdx.x;
    for (int i = tid; i < 64 * 64; i += 512) {
        const int k2 = i >> 6, c = i & 63;
        const float* wp = W1 + (size_t)(2 * k2) * DH + c;
        sW4[k2][c] = make_float4(wp[0], wp[64], wp[DH], wp[DH + 64]);
    }
    __syncthreads();

    const int wave = tid >> 6, lane = tid & 63;
    const float bias0 = b1[lane];
    const float bias1 = b1[64 + lane];

    for (int base = (blockIdx.x * 8 + wave) * 4; base < NN;
         base += gridDim.x * 32) {
        #pragma unroll
        for (int r = 0; r < 4; ++r) {
            const int row = base + r;
            float a0 = 0.f, a1 = 0.f;
            if (row < NN) {
                a0 = x[(size_t)row * DI + lane];
                a1 = x[(size_t)row * DI + 64 + lane];
            }
            float ss = a0 * a0 + a1 * a1;
            #pragma unroll
            for (int off = 32; off; off >>= 1) ss += __shfl_xor(ss, off);
            const float rinv = 1.0f / fmaxf(sqrtf(ss), 1e-12f);
            sx[wave][r][lane]      = a0 * rinv;
            sx[wave][r][64 + lane] = a1 * rinv;
        }

        float acc[4][2];
        #pragma unroll
        for (int r = 0; r < 4; ++r) { acc[r][0] = bias0; acc[r][1] = bias1; }

        #pragma unroll 2
        for (int k2 = 0; k2 < 64; k2 += 2) {
            const float4 w0 = sW4[k2][lane];
            const float4 w1 = sW4[k2 + 1][lane];
            #pragma unroll
            for (int r = 0; r < 4; ++r) {
                const float4 xv = *(const float4*)(&sx[wave][r][2 * k2]);
                acc[r][0] = fmaf(xv.x, w0.x, acc[r][0]);
                acc[r][1] = fmaf(xv.x, w0.y, acc[r][1]);
                acc[r][0] = fmaf(xv.y, w0.z, acc[r][0]);
                acc[r][1] = fmaf(xv.y, w0.w, acc[r][1]);
                acc[r][0] = fmaf(xv.z, w1.x, acc[r][0]);
                acc[r][1] = fmaf(xv.z, w1.y, acc[r][1]);
                acc[r][0] = fmaf(xv.w, w1.z, acc[r][0]);
                acc[r][1] = fmaf(xv.w, w1.w, acc[r][1]);
            }
        }
        #pragma unroll
        for (int r = 0; r < 4; ++r) {
            const int row = base + r;
            if (row < NN) {
                z1h[(size_t)row * DH + lane]      = f2bf(acc[r][0]);
                z1h[(size_t)row * DH + 64 + lane] = f2bf(acc[r][1]);
            }
        }
    }
}

// ---------------------------------------------------------------------------
// One-shot: pack W2 [128][64] fp32 -> bf16 pairs along k:
//   W2p[k2*64+c] = pack(W2[2k2][c] lo, W2[2k2+1][c] hi)
// ---------------------------------------------------------------------------
__global__ __launch_bounds__(256) void k_packW2(
    const float* __restrict__ W2, unsigned* __restrict__ W2p)
{
    const int i = blockIdx.x * 256 + threadIdx.x;   // 4096 total
    const int k2 = i >> 6, c = i & 63;
    const unsigned lo = f2bf(W2[(size_t)(2 * k2) * NC + c]);
    const unsigned hi = f2bf(W2[(size_t)(2 * k2 + 1) * NC + c]);
    W2p[i] = lo | (hi << 16);
}

// ---------------------------------------------------------------------------
// CSR build: histogram -> 3-kernel exclusive scan -> (src,w) scatter
// ---------------------------------------------------------------------------
__global__ __launch_bounds__(256) void k_hist(
    const int* __restrict__ dst, int* __restrict__ cnt)
{
    for (int e = blockIdx.x * 256 + threadIdx.x; e < NE; e += gridDim.x * 256)
        atomicAdd(&cnt[dst[e]], 1);
}

__global__ __launch_bounds__(256) void k_scanA(
    const int* __restrict__ cnt, int* __restrict__ rowptr,
    int* __restrict__ bsum)
{
    __shared__ int tmp[256];
    const int t = threadIdx.x;
    const int gid = blockIdx.x * 256 + t;
    const int v = (gid < NN) ? cnt[gid] : 0;
    tmp[t] = v;
    __syncthreads();
    #pragma unroll
    for (int off = 1; off < 256; off <<= 1) {
        const int add = (t >= off) ? tmp[t - off] : 0;
        __syncthreads();
        tmp[t] += add;
        __syncthreads();
    }
    if (gid < NN) rowptr[gid] = tmp[t] - v;
    if (t == 255) bsum[blockIdx.x] = tmp[255];
}

__global__ __launch_bounds__(512) void k_scanB(int* __restrict__ bsum)
{
    __shared__ int tmp[512];
    const int t = threadIdx.x;
    const int v = (t < NB) ? bsum[t] : 0;
    tmp[t] = v;
    __syncthreads();
    #pragma unroll
    for (int off = 1; off < 512; off <<= 1) {
        const int add = (t >= off) ? tmp[t - off] : 0;
        __syncthreads();
        tmp[t] += add;
        __syncthreads();
    }
    if (t < NB) bsum[t] = tmp[t] - v;
}

__global__ __launch_bounds__(256) void k_scanC(
    int* __restrict__ rowptr, const int* __restrict__ bsum,
    int* __restrict__ offs)
{
    const int gid = blockIdx.x * 256 + threadIdx.x;
    if (gid < NN) {
        const int r = rowptr[gid] + bsum[blockIdx.x];
        rowptr[gid] = r;
        offs[gid]   = r;
    }
    if (gid == 0) rowptr[NN] = NE;
}

__global__ __launch_bounds__(256) void k_scatter(
    const int* __restrict__ src, const int* __restrict__ dst,
    const float* __restrict__ ew, int* __restrict__ offs,
    int2* __restrict__ srcw)
{
    for (int e = blockIdx.x * 256 + threadIdx.x; e < NE; e += gridDim.x * 256) {
        const int pos = atomicAdd(&offs[dst[e]], 1);
        srcw[pos] = make_int2(src[e], __float_as_int(ew[e]));
    }
}

// ---------------------------------------------------------------------------
// Fused: agg = relu(spmm(z1h)); z2 = bf16(agg @ W2 + b2)
// 256 thr, 18KB LDS (bf16 W2) -> 8 blocks/CU; launch_bounds(256,8) pins
// VGPR<=64 -> 32 waves/CU. x8 gather unroll restores per-wave MLP.
// In-flight target: 32 waves x 8 gathers x 4 lines = 1024 lines/CU.
// 32-bit gather offsets (SGPR base + voffset) keep address VGPRs down.
// ---------------------------------------------------------------------------
__global__ __launch_bounds__(256, 8) void k_spmm1_gemm2(
    const unsigned short* __restrict__ h, const int* __restrict__ rowptr,
    const int2* __restrict__ srcw, const unsigned* __restrict__ W2p,
    const float* __restrict__ b2, unsigned short* __restrict__ z2h)
{
    __shared__ unsigned sW2p[64 * 64];   // 16 KB bf16-pair W2
    __shared__ float sagg[4][DH];        // 2 KB

    const int tid = threadIdx.x;
    {
        const uint4* W4 = (const uint4*)W2p;
        uint4* s4 = (uint4*)sW2p;
        #pragma unroll
        for (int i = 0; i < 4; ++i)          // 1024 uint4 / 256
            s4[tid + i * 256] = W4[tid + i * 256];
    }
    __syncthreads();

    const int wave = tid >> 6, lane = tid & 63;
    const float bias = b2[lane];
    const unsigned* hu = (const unsigned*)h;   // 64 uints per row

    for (int row = blockIdx.x * 4 + wave; row < NN; row += gridDim.x * 4) {
        const int start = rowptr[row], end = rowptr[row + 1];
        float acc0 = 0.f, acc1 = 0.f;   // dims 2*lane, 2*lane+1
        int e = start;
        for (; e + 8 <= end; e += 8) {
            const int2 s0 = srcw[e + 0], s1 = srcw[e + 1];
            const int2 s2 = srcw[e + 2], s3 = srcw[e + 3];
            const int2 s4 = srcw[e + 4], s5 = srcw[e + 5];
            const int2 s6 = srcw[e + 6], s7 = srcw[e + 7];
            const unsigned u0 = hu[(((unsigned)s0.x) << 6) | lane];
            const unsigned u1 = hu[(((unsigned)s1.x) << 6) | lane];
            const unsigned u2 = hu[(((unsigned)s2.x) << 6) | lane];
            const unsigned u3 = hu[(((unsigned)s3.x) << 6) | lane];
            const unsigned u4 = hu[(((unsigned)s4.x) << 6) | lane];
            const unsigned u5 = hu[(((unsigned)s5.x) << 6) | lane];
            const unsigned u6 = hu[(((unsigned)s6.x) << 6) | lane];
            const unsigned u7 = hu[(((unsigned)s7.x) << 6) | lane];
            acc0 = fmaf(__int_as_float(s0.y), bf_lo(u0), acc0);
            acc1 = fmaf(__int_as_float(s0.y), bf_hi(u0), acc1);
            acc0 = fmaf(__int_as_float(s1.y), bf_lo(u1), acc0);
            acc1 = fmaf(__int_as_float(s1.y), bf_hi(u1), acc1);
            acc0 = fmaf(__int_as_float(s2.y), bf_lo(u2), acc0);
            acc1 = fmaf(__int_as_float(s2.y), bf_hi(u2), acc1);
            acc0 = fmaf(__int_as_float(s3.y), bf_lo(u3), acc0);
            acc1 = fmaf(__int_as_float(s3.y), bf_hi(u3), acc1);
            acc0 = fmaf(__int_as_float(s4.y), bf_lo(u4), acc0);
            acc1 = fmaf(__int_as_float(s4.y), bf_hi(u4), acc1);
            acc0 = fmaf(__int_as_float(s5.y), bf_lo(u5), acc0);
            acc1 = fmaf(__int_as_float(s5.y), bf_hi(u5), acc1);
            acc0 = fmaf(__int_as_float(s6.y), bf_lo(u6), acc0);
            acc1 = fmaf(__int_as_float(s6.y), bf_hi(u6), acc1);
            acc0 = fmaf(__int_as_float(s7.y), bf_lo(u7), acc0);
            acc1 = fmaf(__int_as_float(s7.y), bf_hi(u7), acc1);
        }
        for (; e + 4 <= end; e += 4) {
            const int2 s0 = srcw[e + 0], s1 = srcw[e + 1];
            const int2 s2 = srcw[e + 2], s3 = srcw[e + 3];
            const unsigned u0 = hu[(((unsigned)s0.x) << 6) | lane];
            const unsigned u1 = hu[(((unsigned)s1.x) << 6) | lane];
            const unsigned u2 = hu[(((unsigned)s2.x) << 6) | lane];
            const unsigned u3 = hu[(((unsigned)s3.x) << 6) | lane];
            acc0 = fmaf(__int_as_float(s0.y), bf_lo(u0), acc0);
            acc1 = fmaf(__int_as_float(s0.y), bf_hi(u0), acc1);
            acc0 = fmaf(__int_as_float(s1.y), bf_lo(u1), acc0);
            acc1 = fmaf(__int_as_float(s1.y), bf_hi(u1), acc1);
            acc0 = fmaf(__int_as_float(s2.y), bf_lo(u2), acc0);
            acc1 = fmaf(__int_as_float(s2.y), bf_hi(u2), acc1);
            acc0 = fmaf(__int_as_float(s3.y), bf_lo(u3), acc0);
            acc1 = fmaf(__int_as_float(s3.y), bf_hi(u3), acc1);
        }
        for (; e < end; ++e) {
            const int2 s = srcw[e];
            const unsigned u = hu[(((unsigned)s.x) << 6) | lane];
            acc0 = fmaf(__int_as_float(s.y), bf_lo(u), acc0);
            acc1 = fmaf(__int_as_float(s.y), bf_hi(u), acc1);
        }
        *(float2*)&sagg[wave][2 * lane] =
            make_float2(fmaxf(acc0, 0.f), fmaxf(acc1, 0.f));

        // z2 = agg @ W2 + b2, W2 as bf16 pairs (k even/odd) in LDS.
        // sW2p read: 64 consecutive uints -> 2 lanes/bank = free.
        float acc = bias;
        #pragma unroll 8
        for (int k2 = 0; k2 < 64; ++k2) {
            const unsigned w = sW2p[k2 * 64 + lane];
            const float2 a = *(const float2*)(&sagg[wave][2 * k2]);  // broadcast
            acc = fmaf(a.x, bf_lo(w), acc);
            acc = fmaf(a.y, bf_hi(w), acc);
        }
        z2h[(size_t)row * NC + lane] = f2bf(acc);
    }
}

// ---------------------------------------------------------------------------
// Gather-SPMM D=64 (bf16 table) + fused softmax, x8 edge unroll
// ---------------------------------------------------------------------------
__global__ __launch_bounds__(256, 8) void k_spmm2_softmax(
    const unsigned short* __restrict__ z2h, const int* __restrict__ rowptr,
    const int2* __restrict__ srcw, float* __restrict__ out)
{
    const int row = blockIdx.x * 4 + (threadIdx.x >> 6);
    if (row >= NN) return;
    const int lane = threadIdx.x & 63;
    const int start = rowptr[row], end = rowptr[row + 1];
    float acc = 0.f;
    int e = start;
    for (; e + 8 <= end; e += 8) {
        const int2 s0 = srcw[e + 0], s1 = srcw[e + 1];
        const int2 s2 = srcw[e + 2], s3 = srcw[e + 3];
        const int2 s4 = srcw[e + 4], s5 = srcw[e + 5];
        const int2 s6 = srcw[e + 6], s7 = srcw[e + 7];
        const unsigned short t0 = z2h[(((unsigned)s0.x) << 6) | lane];
        const unsigned short t1 = z2h[(((unsigned)s1.x) << 6) | lane];
        const unsigned short t2 = z2h[(((unsigned)s2.x) << 6) | lane];
        const unsigned short t3 = z2h[(((unsigned)s3.x) << 6) | lane];
        const unsigned short t4 = z2h[(((unsigned)s4.x) << 6) | lane];
        const unsigned short t5 = z2h[(((unsigned)s5.x) << 6) | lane];
        const unsigned short t6 = z2h[(((unsigned)s6.x) << 6) | lane];
        const unsigned short t7 = z2h[(((unsigned)s7.x) << 6) | lane];
        acc = fmaf(__int_as_float(s0.y), __uint_as_float((unsigned)t0 << 16), acc);
        acc = fmaf(__int_as_float(s1.y), __uint_as_float((unsigned)t1 << 16), acc);
        acc = fmaf(__int_as_float(s2.y), __uint_as_float((unsigned)t2 << 16), acc);
        acc = fmaf(__int_as_float(s3.y), __uint_as_float((unsigned)t3 << 16), acc);
        acc = fmaf(__int_as_float(s4.y), __uint_as_float((unsigned)t4 << 16), acc);
        acc = fmaf(__int_as_float(s5.y), __uint_as_float((unsigned)t5 << 16), acc);
        acc = fmaf(__int_as_float(s6.y), __uint_as_float((unsigned)t6 << 16), acc);
        acc = fmaf(__int_as_float(s7.y), __uint_as_float((unsigned)t7 << 16), acc);
    }
    for (; e + 4 <= end; e += 4) {
        const int2 s0 = srcw[e + 0], s1 = srcw[e + 1];
        const int2 s2 = srcw[e + 2], s3 = srcw[e + 3];
        const unsigned short t0 = z2h[(((unsigned)s0.x) << 6) | lane];
        const unsigned short t1 = z2h[(((unsigned)s1.x) << 6) | lane];
        const unsigned short t2 = z2h[(((unsigned)s2.x) << 6) | lane];
        const unsigned short t3 = z2h[(((unsigned)s3.x) << 6) | lane];
        acc = fmaf(__int_as_float(s0.y), __uint_as_float((unsigned)t0 << 16), acc);
        acc = fmaf(__int_as_float(s1.y), __uint_as_float((unsigned)t1 << 16), acc);
        acc = fmaf(__int_as_float(s2.y), __uint_as_float((unsigned)t2 << 16), acc);
        acc = fmaf(__int_as_float(s3.y), __uint_as_float((unsigned)t3 << 16), acc);
    }
    for (; e < end; ++e) {
        const int2 s = srcw[e];
        const float v = __uint_as_float(
            (unsigned)z2h[(((unsigned)s.x) << 6) | lane] << 16);
        acc = fmaf(__int_as_float(s.y), v, acc);
    }
    float m = acc;
    #pragma unroll
    for (int off = 32; off; off >>= 1) m = fmaxf(m, __shfl_xor(m, off));
    const float ex = __expf(acc - m);
    float s = ex;
    #pragma unroll
    for (int off = 32; off; off >>= 1) s += __shfl_xor(s, off);
    out[(size_t)row * NC + lane] = ex / s;
}

// ---------------------------------------------------------------------------
extern "C" void kernel_launch(void* const* d_in, const int* in_sizes, int n_in,
                              void* d_out, int out_size, void* d_ws,
                              size_t ws_size, hipStream_t stream)
{
    const float* x  = (const float*)d_in[0];
    const int* src  = (const int*)d_in[1];
    const int* dst  = (const int*)d_in[2];
    const float* ew = (const float*)d_in[3];
    const float* W1 = (const float*)d_in[4];
    const float* b1 = (const float*)d_in[5];
    const float* W2 = (const float*)d_in[6];
    const float* b2 = (const float*)d_in[7];
    float* out = (float*)d_out;

    char* base = (char*)d_ws;
    unsigned short* z1h = (unsigned short*)base;  base += (size_t)NN * DH * 2;
    unsigned short* z2h = (unsigned short*)base;  base += (size_t)NN * NC * 2;
    int2*  srcw = (int2*)base;                    base += (size_t)NE * 8;
    int* rowptr = (int*)base;                     base += ((size_t)NN + 2) * 4;
    int* offs   = (int*)base;                     base += (size_t)NN * 4;
    int* bsum   = (int*)base;                     base += 512 * 4;
    unsigned* W2p = (unsigned*)base;              base += 4096 * 4;
    int* cnt    = offs;                           // cnt dead after scanA

    hipMemsetAsync(cnt, 0, (size_t)NN * 4, stream);

    k_packW2<<<16, 256, 0, stream>>>(W2, W2p);
    k_norm_gemm1<<<1024, 512, 0, stream>>>(x, W1, b1, z1h);

    k_hist   <<<2048, 256, 0, stream>>>(dst, cnt);
    k_scanA  <<<NB, 256, 0, stream>>>(cnt, rowptr, bsum);
    k_scanB  <<<1, 512, 0, stream>>>(bsum);
    k_scanC  <<<NB, 256, 0, stream>>>(rowptr, bsum, offs);
    k_scatter<<<2048, 256, 0, stream>>>(src, dst, ew, offs, srcw);

    k_spmm1_gemm2   <<<2048, 256, 0, stream>>>(z1h, rowptr, srcw, W2p, b2, z2h);
    k_spmm2_softmax <<<(NN + 3) / 4, 256, 0, stream>>>(z2h, rowptr, srcw, out);
}

// Round 9
// 323.873 us; speedup vs baseline: 1.5415x; 1.2402x over previous
//
#include <hip/hip_runtime.h>
#include <math.h>

constexpr int NN = 100000;   // nodes
constexpr int NE = 1600000;  // edges
constexpr int DI = 128;      // input dim
constexpr int DH = 128;      // hidden dim
constexpr int NC = 64;       // classes
constexpr int NB = (NN + 255) / 256;   // 391 scan blocks

// bf16 pack/unpack (RNE). Internal z1/z2 and W2 stored bf16.
__device__ __forceinline__ unsigned short f2bf(float f) {
    const unsigned u = __float_as_uint(f);
    return (unsigned short)((u + 0x7FFFu + ((u >> 16) & 1u)) >> 16);
}
__device__ __forceinline__ float bf_lo(unsigned u) {
    return __uint_as_float(u << 16);
}
__device__ __forceinline__ float bf_hi(unsigned u) {
    return __uint_as_float(u & 0xFFFF0000u);
}
// packed edge record: (src << 15) | wq, wq = round(w * 32767)
constexpr float INV_WQ = 1.0f / 32767.0f;

// ---------------------------------------------------------------------------
// Kernel 1: z1 = bf16(l2normalize(x) @ W1 + b1)  (round-5 structure, proven)
// ---------------------------------------------------------------------------
__global__ __launch_bounds__(512) void k_norm_gemm1(
    const float* __restrict__ x, const float* __restrict__ W1,
    const float* __restrict__ b1, unsigned short* __restrict__ z1h)
{
    __shared__ float4 sW4[64][64];   // 64 KB quad-paired
    __shared__ float sx[8][4][DI];   // 16 KB

    const int tid = threadIdx.x;
    for (int i = tid; i < 64 * 64; i += 512) {
        const int k2 = i >> 6, c = i & 63;
        const float* wp = W1 + (size_t)(2 * k2) * DH + c;
        sW4[k2][c] = make_float4(wp[0], wp[64], wp[DH], wp[DH + 64]);
    }
    __syncthreads();

    const int wave = tid >> 6, lane = tid & 63;
    const float bias0 = b1[lane];
    const float bias1 = b1[64 + lane];

    for (int base = (blockIdx.x * 8 + wave) * 4; base < NN;
         base += gridDim.x * 32) {
        #pragma unroll
        for (int r = 0; r < 4; ++r) {
            const int row = base + r;
            float a0 = 0.f, a1 = 0.f;
            if (row < NN) {
                a0 = x[(size_t)row * DI + lane];
                a1 = x[(size_t)row * DI + 64 + lane];
            }
            float ss = a0 * a0 + a1 * a1;
            #pragma unroll
            for (int off = 32; off; off >>= 1) ss += __shfl_xor(ss, off);
            const float rinv = 1.0f / fmaxf(sqrtf(ss), 1e-12f);
            sx[wave][r][lane]      = a0 * rinv;
            sx[wave][r][64 + lane] = a1 * rinv;
        }

        float acc[4][2];
        #pragma unroll
        for (int r = 0; r < 4; ++r) { acc[r][0] = bias0; acc[r][1] = bias1; }

        #pragma unroll 2
        for (int k2 = 0; k2 < 64; k2 += 2) {
            const float4 w0 = sW4[k2][lane];
            const float4 w1 = sW4[k2 + 1][lane];
            #pragma unroll
            for (int r = 0; r < 4; ++r) {
                const float4 xv = *(const float4*)(&sx[wave][r][2 * k2]);
                acc[r][0] = fmaf(xv.x, w0.x, acc[r][0]);
                acc[r][1] = fmaf(xv.x, w0.y, acc[r][1]);
                acc[r][0] = fmaf(xv.y, w0.z, acc[r][0]);
                acc[r][1] = fmaf(xv.y, w0.w, acc[r][1]);
                acc[r][0] = fmaf(xv.z, w1.x, acc[r][0]);
                acc[r][1] = fmaf(xv.z, w1.y, acc[r][1]);
                acc[r][0] = fmaf(xv.w, w1.z, acc[r][0]);
                acc[r][1] = fmaf(xv.w, w1.w, acc[r][1]);
            }
        }
        #pragma unroll
        for (int r = 0; r < 4; ++r) {
            const int row = base + r;
            if (row < NN) {
                z1h[(size_t)row * DH + lane]      = f2bf(acc[r][0]);
                z1h[(size_t)row * DH + 64 + lane] = f2bf(acc[r][1]);
            }
        }
    }
}

// ---------------------------------------------------------------------------
// One-shot: pack W2 [128][64] fp32 -> bf16 pairs along k.
// ---------------------------------------------------------------------------
__global__ __launch_bounds__(256) void k_packW2(
    const float* __restrict__ W2, unsigned* __restrict__ W2p)
{
    const int i = blockIdx.x * 256 + threadIdx.x;   // 4096 total
    const int k2 = i >> 6, c = i & 63;
    const unsigned lo = f2bf(W2[(size_t)(2 * k2) * NC + c]);
    const unsigned hi = f2bf(W2[(size_t)(2 * k2 + 1) * NC + c]);
    W2p[i] = lo | (hi << 16);
}

// ---------------------------------------------------------------------------
// CSR build: rank-fused histogram -> 3-kernel scan -> atomic-free scatter
// ---------------------------------------------------------------------------
__global__ __launch_bounds__(256) void k_hist(
    const int* __restrict__ dst, int* __restrict__ cnt,
    int* __restrict__ rank)
{
    for (int e = blockIdx.x * 256 + threadIdx.x; e < NE; e += gridDim.x * 256)
        rank[e] = atomicAdd(&cnt[dst[e]], 1);   // rank write is coalesced
}

__global__ __launch_bounds__(256) void k_scanA(
    const int* __restrict__ cnt, int* __restrict__ rowptr,
    int* __restrict__ bsum)
{
    __shared__ int tmp[256];
    const int t = threadIdx.x;
    const int gid = blockIdx.x * 256 + t;
    const int v = (gid < NN) ? cnt[gid] : 0;
    tmp[t] = v;
    __syncthreads();
    #pragma unroll
    for (int off = 1; off < 256; off <<= 1) {
        const int add = (t >= off) ? tmp[t - off] : 0;
        __syncthreads();
        tmp[t] += add;
        __syncthreads();
    }
    if (gid < NN) rowptr[gid] = tmp[t] - v;
    if (t == 255) bsum[blockIdx.x] = tmp[255];
}

__global__ __launch_bounds__(512) void k_scanB(int* __restrict__ bsum)
{
    __shared__ int tmp[512];
    const int t = threadIdx.x;
    const int v = (t < NB) ? bsum[t] : 0;
    tmp[t] = v;
    __syncthreads();
    #pragma unroll
    for (int off = 1; off < 512; off <<= 1) {
        const int add = (t >= off) ? tmp[t - off] : 0;
        __syncthreads();
        tmp[t] += add;
        __syncthreads();
    }
    if (t < NB) bsum[t] = tmp[t] - v;
}

__global__ __launch_bounds__(256) void k_scanC(
    int* __restrict__ rowptr, const int* __restrict__ bsum)
{
    const int gid = blockIdx.x * 256 + threadIdx.x;
    if (gid < NN) rowptr[gid] += bsum[blockIdx.x];
    if (gid == 0) rowptr[NN] = NE;
}

__global__ __launch_bounds__(256) void k_scatter(
    const int* __restrict__ src, const int* __restrict__ dst,
    const float* __restrict__ ew, const int* __restrict__ rowptr,
    const int* __restrict__ rank, unsigned* __restrict__ srcw)
{
    for (int e = blockIdx.x * 256 + threadIdx.x; e < NE; e += gridDim.x * 256) {
        const int pos = rowptr[dst[e]] + rank[e];      // no atomics
        const unsigned wq = (unsigned)__float2int_rn(ew[e] * 32767.f);
        srcw[pos] = (((unsigned)src[e]) << 15) | wq;   // 4B payload
    }
}

// ---------------------------------------------------------------------------
// Fused: agg = relu(spmm(z1h)); z2 = bf16(agg @ W2 + b2)
// 256 thr, 18KB LDS, launch_bounds(256,8): 8 blocks/CU, 32 waves/CU.
// x8 gather unroll; packed 4B edge records (src:17 | wq:15).
// ---------------------------------------------------------------------------
__global__ __launch_bounds__(256, 8) void k_spmm1_gemm2(
    const unsigned short* __restrict__ h, const int* __restrict__ rowptr,
    const unsigned* __restrict__ srcw, const unsigned* __restrict__ W2p,
    const float* __restrict__ b2, unsigned short* __restrict__ z2h)
{
    __shared__ unsigned sW2p[64 * 64];   // 16 KB bf16-pair W2
    __shared__ float sagg[4][DH];        // 2 KB

    const int tid = threadIdx.x;
    {
        const uint4* W4 = (const uint4*)W2p;
        uint4* s4 = (uint4*)sW2p;
        #pragma unroll
        for (int i = 0; i < 4; ++i)
            s4[tid + i * 256] = W4[tid + i * 256];
    }
    __syncthreads();

    const int wave = tid >> 6, lane = tid & 63;
    const float bias = b2[lane];
    const unsigned* hu = (const unsigned*)h;   // 64 uints per row

    for (int row = blockIdx.x * 4 + wave; row < NN; row += gridDim.x * 4) {
        const int start = rowptr[row], end = rowptr[row + 1];
        float acc0 = 0.f, acc1 = 0.f;   // dims 2*lane, 2*lane+1
        int e = start;
        for (; e + 8 <= end; e += 8) {
            const unsigned p0 = srcw[e + 0], p1 = srcw[e + 1];
            const unsigned p2 = srcw[e + 2], p3 = srcw[e + 3];
            const unsigned p4 = srcw[e + 4], p5 = srcw[e + 5];
            const unsigned p6 = srcw[e + 6], p7 = srcw[e + 7];
            const unsigned u0 = hu[((p0 >> 15) << 6) | lane];
            const unsigned u1 = hu[((p1 >> 15) << 6) | lane];
            const unsigned u2 = hu[((p2 >> 15) << 6) | lane];
            const unsigned u3 = hu[((p3 >> 15) << 6) | lane];
            const unsigned u4 = hu[((p4 >> 15) << 6) | lane];
            const unsigned u5 = hu[((p5 >> 15) << 6) | lane];
            const unsigned u6 = hu[((p6 >> 15) << 6) | lane];
            const unsigned u7 = hu[((p7 >> 15) << 6) | lane];
            const float w0 = (float)(p0 & 0x7FFFu) * INV_WQ;
            const float w1 = (float)(p1 & 0x7FFFu) * INV_WQ;
            const float w2 = (float)(p2 & 0x7FFFu) * INV_WQ;
            const float w3 = (float)(p3 & 0x7FFFu) * INV_WQ;
            const float w4 = (float)(p4 & 0x7FFFu) * INV_WQ;
            const float w5 = (float)(p5 & 0x7FFFu) * INV_WQ;
            const float w6 = (float)(p6 & 0x7FFFu) * INV_WQ;
            const float w7 = (float)(p7 & 0x7FFFu) * INV_WQ;
            acc0 = fmaf(w0, bf_lo(u0), acc0); acc1 = fmaf(w0, bf_hi(u0), acc1);
            acc0 = fmaf(w1, bf_lo(u1), acc0); acc1 = fmaf(w1, bf_hi(u1), acc1);
            acc0 = fmaf(w2, bf_lo(u2), acc0); acc1 = fmaf(w2, bf_hi(u2), acc1);
            acc0 = fmaf(w3, bf_lo(u3), acc0); acc1 = fmaf(w3, bf_hi(u3), acc1);
            acc0 = fmaf(w4, bf_lo(u4), acc0); acc1 = fmaf(w4, bf_hi(u4), acc1);
            acc0 = fmaf(w5, bf_lo(u5), acc0); acc1 = fmaf(w5, bf_hi(u5), acc1);
            acc0 = fmaf(w6, bf_lo(u6), acc0); acc1 = fmaf(w6, bf_hi(u6), acc1);
            acc0 = fmaf(w7, bf_lo(u7), acc0); acc1 = fmaf(w7, bf_hi(u7), acc1);
        }
        for (; e < end; ++e) {
            const unsigned p = srcw[e];
            const unsigned u = hu[((p >> 15) << 6) | lane];
            const float w = (float)(p & 0x7FFFu) * INV_WQ;
            acc0 = fmaf(w, bf_lo(u), acc0);
            acc1 = fmaf(w, bf_hi(u), acc1);
        }
        *(float2*)&sagg[wave][2 * lane] =
            make_float2(fmaxf(acc0, 0.f), fmaxf(acc1, 0.f));

        float acc = bias;
        #pragma unroll 8
        for (int k2 = 0; k2 < 64; ++k2) {
            const unsigned w = sW2p[k2 * 64 + lane];
            const float2 a = *(const float2*)(&sagg[wave][2 * k2]);
            acc = fmaf(a.x, bf_lo(w), acc);
            acc = fmaf(a.y, bf_hi(w), acc);
        }
        z2h[(size_t)row * NC + lane] = f2bf(acc);
    }
}

// ---------------------------------------------------------------------------
// Gather-SPMM D=64 (bf16 table) + fused softmax, x8 edge unroll
// ---------------------------------------------------------------------------
__global__ __launch_bounds__(256, 8) void k_spmm2_softmax(
    const unsigned short* __restrict__ z2h, const int* __restrict__ rowptr,
    const unsigned* __restrict__ srcw, float* __restrict__ out)
{
    const int row = blockIdx.x * 4 + (threadIdx.x >> 6);
    if (row >= NN) return;
    const int lane = threadIdx.x & 63;
    const int start = rowptr[row], end = rowptr[row + 1];
    float acc = 0.f;
    int e = start;
    for (; e + 8 <= end; e += 8) {
        const unsigned p0 = srcw[e + 0], p1 = srcw[e + 1];
        const unsigned p2 = srcw[e + 2], p3 = srcw[e + 3];
        const unsigned p4 = srcw[e + 4], p5 = srcw[e + 5];
        const unsigned p6 = srcw[e + 6], p7 = srcw[e + 7];
        const unsigned short t0 = z2h[((p0 >> 15) << 6) | lane];
        const unsigned short t1 = z2h[((p1 >> 15) << 6) | lane];
        const unsigned short t2 = z2h[((p2 >> 15) << 6) | lane];
        const unsigned short t3 = z2h[((p3 >> 15) << 6) | lane];
        const unsigned short t4 = z2h[((p4 >> 15) << 6) | lane];
        const unsigned short t5 = z2h[((p5 >> 15) << 6) | lane];
        const unsigned short t6 = z2h[((p6 >> 15) << 6) | lane];
        const unsigned short t7 = z2h[((p7 >> 15) << 6) | lane];
        acc = fmaf((float)(p0 & 0x7FFFu) * INV_WQ,
                   __uint_as_float((unsigned)t0 << 16), acc);
        acc = fmaf((float)(p1 & 0x7FFFu) * INV_WQ,
                   __uint_as_float((unsigned)t1 << 16), acc);
        acc = fmaf((float)(p2 & 0x7FFFu) * INV_WQ,
                   __uint_as_float((unsigned)t2 << 16), acc);
        acc = fmaf((float)(p3 & 0x7FFFu) * INV_WQ,
                   __uint_as_float((unsigned)t3 << 16), acc);
        acc = fmaf((float)(p4 & 0x7FFFu) * INV_WQ,
                   __uint_as_float((unsigned)t4 << 16), acc);
        acc = fmaf((float)(p5 & 0x7FFFu) * INV_WQ,
                   __uint_as_float((unsigned)t5 << 16), acc);
        acc = fmaf((float)(p6 & 0x7FFFu) * INV_WQ,
                   __uint_as_float((unsigned)t6 << 16), acc);
        acc = fmaf((float)(p7 & 0x7FFFu) * INV_WQ,
                   __uint_as_float((unsigned)t7 << 16), acc);
    }
    for (; e < end; ++e) {
        const unsigned p = srcw[e];
        const float v = __uint_as_float(
            (unsigned)z2h[((p >> 15) << 6) | lane] << 16);
        acc = fmaf((float)(p & 0x7FFFu) * INV_WQ, v, acc);
    }
    float m = acc;
    #pragma unroll
    for (int off = 32; off; off >>= 1) m = fmaxf(m, __shfl_xor(m, off));
    const float ex = __expf(acc - m);
    float s = ex;
    #pragma unroll
    for (int off = 32; off; off >>= 1) s += __shfl_xor(s, off);
    out[(size_t)row * NC + lane] = ex / s;
}

// ---------------------------------------------------------------------------
extern "C" void kernel_launch(void* const* d_in, const int* in_sizes, int n_in,
                              void* d_out, int out_size, void* d_ws,
                              size_t ws_size, hipStream_t stream)
{
    const float* x  = (const float*)d_in[0];
    const int* src  = (const int*)d_in[1];
    const int* dst  = (const int*)d_in[2];
    const float* ew = (const float*)d_in[3];
    const float* W1 = (const float*)d_in[4];
    const float* b1 = (const float*)d_in[5];
    const float* W2 = (const float*)d_in[6];
    const float* b2 = (const float*)d_in[7];
    float* out = (float*)d_out;

    char* base = (char*)d_ws;
    unsigned short* z1h = (unsigned short*)base;  base += (size_t)NN * DH * 2;
    unsigned short* z2h = (unsigned short*)base;  base += (size_t)NN * NC * 2;
    unsigned* srcw = (unsigned*)base;             base += (size_t)NE * 4;
    int* rank   = (int*)base;                     base += (size_t)NE * 4;
    int* rowptr = (int*)base;                     base += ((size_t)NN + 2) * 4;
    int* cnt    = (int*)base;                     base += (size_t)NN * 4;
    int* bsum   = (int*)base;                     base += 512 * 4;
    unsigned* W2p = (unsigned*)base;              base += 4096 * 4;

    hipMemsetAsync(cnt, 0, (size_t)NN * 4, stream);

    k_packW2<<<16, 256, 0, stream>>>(W2, W2p);
    k_norm_gemm1<<<1024, 512, 0, stream>>>(x, W1, b1, z1h);

    k_hist   <<<2048, 256, 0, stream>>>(dst, cnt, rank);
    k_scanA  <<<NB, 256, 0, stream>>>(cnt, rowptr, bsum);
    k_scanB  <<<1, 512, 0, stream>>>(bsum);
    k_scanC  <<<NB, 256, 0, stream>>>(rowptr, bsum);
    k_scatter<<<2048, 256, 0, stream>>>(src, dst, ew, rowptr, rank, srcw);

    k_spmm1_gemm2   <<<2048, 256, 0, stream>>>(z1h, rowptr, srcw, W2p, b2, z2h);
    k_spmm2_softmax <<<(NN + 3) / 4, 256, 0, stream>>>(z2h, rowptr, srcw, out);
}

// Round 10
// 320.871 us; speedup vs baseline: 1.5560x; 1.0094x over previous
//
#include <hip/hip_runtime.h>
#include <math.h>

constexpr int NN = 100000;   // nodes
constexpr int NE = 1600000;  // edges
constexpr int DI = 128;      // input dim
constexpr int DH = 128;      // hidden dim
constexpr int NC = 64;       // classes
constexpr int NB = (NN + 255) / 256;   // 391 scan blocks

// bf16 pack/unpack (RNE). Internal z1/z2 stored bf16.
__device__ __forceinline__ unsigned short f2bf(float f) {
    const unsigned u = __float_as_uint(f);
    return (unsigned short)((u + 0x7FFFu + ((u >> 16) & 1u)) >> 16);
}
__device__ __forceinline__ float bf_lo(unsigned u) {
    return __uint_as_float(u << 16);
}
__device__ __forceinline__ float bf_hi(unsigned u) {
    return __uint_as_float(u & 0xFFFF0000u);
}
// packed edge record: (src << 15) | wq, wq = round(w * 32767)
constexpr float INV_WQ = 1.0f / 32767.0f;

// ---------------------------------------------------------------------------
// Kernel 1: z1 = bf16(l2normalize(x) @ W1 + b1)  (round-5 structure, proven)
// ---------------------------------------------------------------------------
__global__ __launch_bounds__(512) void k_norm_gemm1(
    const float* __restrict__ x, const float* __restrict__ W1,
    const float* __restrict__ b1, unsigned short* __restrict__ z1h)
{
    __shared__ float4 sW4[64][64];   // 64 KB quad-paired
    __shared__ float sx[8][4][DI];   // 16 KB

    const int tid = threadIdx.x;
    for (int i = tid; i < 64 * 64; i += 512) {
        const int k2 = i >> 6, c = i & 63;
        const float* wp = W1 + (size_t)(2 * k2) * DH + c;
        sW4[k2][c] = make_float4(wp[0], wp[64], wp[DH], wp[DH + 64]);
    }
    __syncthreads();

    const int wave = tid >> 6, lane = tid & 63;
    const float bias0 = b1[lane];
    const float bias1 = b1[64 + lane];

    for (int base = (blockIdx.x * 8 + wave) * 4; base < NN;
         base += gridDim.x * 32) {
        #pragma unroll
        for (int r = 0; r < 4; ++r) {
            const int row = base + r;
            float a0 = 0.f, a1 = 0.f;
            if (row < NN) {
                a0 = x[(size_t)row * DI + lane];
                a1 = x[(size_t)row * DI + 64 + lane];
            }
            float ss = a0 * a0 + a1 * a1;
            #pragma unroll
            for (int off = 32; off; off >>= 1) ss += __shfl_xor(ss, off);
            const float rinv = 1.0f / fmaxf(sqrtf(ss), 1e-12f);
            sx[wave][r][lane]      = a0 * rinv;
            sx[wave][r][64 + lane] = a1 * rinv;
        }

        float acc[4][2];
        #pragma unroll
        for (int r = 0; r < 4; ++r) { acc[r][0] = bias0; acc[r][1] = bias1; }

        #pragma unroll 2
        for (int k2 = 0; k2 < 64; k2 += 2) {
            const float4 w0 = sW4[k2][lane];
            const float4 w1 = sW4[k2 + 1][lane];
            #pragma unroll
            for (int r = 0; r < 4; ++r) {
                const float4 xv = *(const float4*)(&sx[wave][r][2 * k2]);
                acc[r][0] = fmaf(xv.x, w0.x, acc[r][0]);
                acc[r][1] = fmaf(xv.x, w0.y, acc[r][1]);
                acc[r][0] = fmaf(xv.y, w0.z, acc[r][0]);
                acc[r][1] = fmaf(xv.y, w0.w, acc[r][1]);
                acc[r][0] = fmaf(xv.z, w1.x, acc[r][0]);
                acc[r][1] = fmaf(xv.z, w1.y, acc[r][1]);
                acc[r][0] = fmaf(xv.w, w1.z, acc[r][0]);
                acc[r][1] = fmaf(xv.w, w1.w, acc[r][1]);
            }
        }
        #pragma unroll
        for (int r = 0; r < 4; ++r) {
            const int row = base + r;
            if (row < NN) {
                z1h[(size_t)row * DH + lane]      = f2bf(acc[r][0]);
                z1h[(size_t)row * DH + 64 + lane] = f2bf(acc[r][1]);
            }
        }
    }
}

// ---------------------------------------------------------------------------
// One-shot: pack W2 [128][64] fp32 -> k-quads: W2q[k4*64+c] = W2[4k4..4k4+3][c]
// ---------------------------------------------------------------------------
__global__ __launch_bounds__(256) void k_packW2q(
    const float* __restrict__ W2, float4* __restrict__ W2q)
{
    const int i = blockIdx.x * 256 + threadIdx.x;   // 2048 total
    const int k4 = i >> 6, c = i & 63;
    W2q[i] = make_float4(W2[(size_t)(4 * k4 + 0) * NC + c],
                         W2[(size_t)(4 * k4 + 1) * NC + c],
                         W2[(size_t)(4 * k4 + 2) * NC + c],
                         W2[(size_t)(4 * k4 + 3) * NC + c]);
}

// ---------------------------------------------------------------------------
// CSR build: rank-fused histogram -> 3-kernel scan -> atomic-free scatter
// ---------------------------------------------------------------------------
__global__ __launch_bounds__(256) void k_hist(
    const int* __restrict__ dst, int* __restrict__ cnt,
    int* __restrict__ rank)
{
    for (int e = blockIdx.x * 256 + threadIdx.x; e < NE; e += gridDim.x * 256)
        rank[e] = atomicAdd(&cnt[dst[e]], 1);   // rank write is coalesced
}

__global__ __launch_bounds__(256) void k_scanA(
    const int* __restrict__ cnt, int* __restrict__ rowptr,
    int* __restrict__ bsum)
{
    __shared__ int tmp[256];
    const int t = threadIdx.x;
    const int gid = blockIdx.x * 256 + t;
    const int v = (gid < NN) ? cnt[gid] : 0;
    tmp[t] = v;
    __syncthreads();
    #pragma unroll
    for (int off = 1; off < 256; off <<= 1) {
        const int add = (t >= off) ? tmp[t - off] : 0;
        __syncthreads();
        tmp[t] += add;
        __syncthreads();
    }
    if (gid < NN) rowptr[gid] = tmp[t] - v;
    if (t == 255) bsum[blockIdx.x] = tmp[255];
}

__global__ __launch_bounds__(512) void k_scanB(int* __restrict__ bsum)
{
    __shared__ int tmp[512];
    const int t = threadIdx.x;
    const int v = (t < NB) ? bsum[t] : 0;
    tmp[t] = v;
    __syncthreads();
    #pragma unroll
    for (int off = 1; off < 512; off <<= 1) {
        const int add = (t >= off) ? tmp[t - off] : 0;
        __syncthreads();
        tmp[t] += add;
        __syncthreads();
    }
    if (t < NB) bsum[t] = tmp[t] - v;
}

__global__ __launch_bounds__(256) void k_scanC(
    int* __restrict__ rowptr, const int* __restrict__ bsum)
{
    const int gid = blockIdx.x * 256 + threadIdx.x;
    if (gid < NN) rowptr[gid] += bsum[blockIdx.x];
    if (gid == 0) rowptr[NN] = NE;
}

__global__ __launch_bounds__(256) void k_scatter(
    const int* __restrict__ src, const int* __restrict__ dst,
    const float* __restrict__ ew, const int* __restrict__ rowptr,
    const int* __restrict__ rank, unsigned* __restrict__ srcw)
{
    for (int e = blockIdx.x * 256 + threadIdx.x; e < NE; e += gridDim.x * 256) {
        const int pos = rowptr[dst[e]] + rank[e];      // no atomics
        const unsigned wq = (unsigned)__float2int_rn(ew[e] * 32767.f);
        srcw[pos] = (((unsigned)src[e]) << 15) | wq;   // 4B payload
    }
}

// ---------------------------------------------------------------------------
// Fused: agg = relu(spmm(z1h)); z2 = bf16(agg @ W2 + b2)
// 512 thr, 36KB LDS (fp32-quad W2 32KB + sagg 4KB) -> 4 blocks/CU
// = 32 waves/CU (same occupancy as R9's 8x256).
// Epilogue: 32 x (ds_read_b128 W-quad + uniform ds_read_b128 sagg + 4 FMA)
// -- zero per-FMA unpack VALU (R9: 85% VALUBusy, epilogue was ~half the
// instructions due to bf16-pair unpacks). Gather loop unchanged (proven).
// ---------------------------------------------------------------------------
__global__ __launch_bounds__(512, 4) void k_spmm1_gemm2(
    const unsigned short* __restrict__ h, const int* __restrict__ rowptr,
    const unsigned* __restrict__ srcw, const float4* __restrict__ W2q,
    const float* __restrict__ b2, unsigned short* __restrict__ z2h)
{
    __shared__ float4 sW2q[32 * 64];   // 32 KB fp32 k-quad W2
    __shared__ float sagg[8][DH];      // 4 KB

    const int tid = threadIdx.x;
    #pragma unroll
    for (int i = 0; i < 4; ++i)        // 2048 float4 / 512
        sW2q[tid + i * 512] = W2q[tid + i * 512];
    __syncthreads();

    const int wave = tid >> 6, lane = tid & 63;
    const float bias = b2[lane];
    const unsigned* hu = (const unsigned*)h;   // 64 uints per row

    for (int row = blockIdx.x * 8 + wave; row < NN; row += gridDim.x * 8) {
        const int start = rowptr[row], end = rowptr[row + 1];
        float acc0 = 0.f, acc1 = 0.f;   // dims 2*lane, 2*lane+1
        int e = start;
        for (; e + 8 <= end; e += 8) {
            const unsigned p0 = srcw[e + 0], p1 = srcw[e + 1];
            const unsigned p2 = srcw[e + 2], p3 = srcw[e + 3];
            const unsigned p4 = srcw[e + 4], p5 = srcw[e + 5];
            const unsigned p6 = srcw[e + 6], p7 = srcw[e + 7];
            const unsigned u0 = hu[((p0 >> 15) << 6) | lane];
            const unsigned u1 = hu[((p1 >> 15) << 6) | lane];
            const unsigned u2 = hu[((p2 >> 15) << 6) | lane];
            const unsigned u3 = hu[((p3 >> 15) << 6) | lane];
            const unsigned u4 = hu[((p4 >> 15) << 6) | lane];
            const unsigned u5 = hu[((p5 >> 15) << 6) | lane];
            const unsigned u6 = hu[((p6 >> 15) << 6) | lane];
            const unsigned u7 = hu[((p7 >> 15) << 6) | lane];
            const float w0 = (float)(p0 & 0x7FFFu) * INV_WQ;
            const float w1 = (float)(p1 & 0x7FFFu) * INV_WQ;
            const float w2 = (float)(p2 & 0x7FFFu) * INV_WQ;
            const float w3 = (float)(p3 & 0x7FFFu) * INV_WQ;
            const float w4 = (float)(p4 & 0x7FFFu) * INV_WQ;
            const float w5 = (float)(p5 & 0x7FFFu) * INV_WQ;
            const float w6 = (float)(p6 & 0x7FFFu) * INV_WQ;
            const float w7 = (float)(p7 & 0x7FFFu) * INV_WQ;
            acc0 = fmaf(w0, bf_lo(u0), acc0); acc1 = fmaf(w0, bf_hi(u0), acc1);
            acc0 = fmaf(w1, bf_lo(u1), acc0); acc1 = fmaf(w1, bf_hi(u1), acc1);
            acc0 = fmaf(w2, bf_lo(u2), acc0); acc1 = fmaf(w2, bf_hi(u2), acc1);
            acc0 = fmaf(w3, bf_lo(u3), acc0); acc1 = fmaf(w3, bf_hi(u3), acc1);
            acc0 = fmaf(w4, bf_lo(u4), acc0); acc1 = fmaf(w4, bf_hi(u4), acc1);
            acc0 = fmaf(w5, bf_lo(u5), acc0); acc1 = fmaf(w5, bf_hi(u5), acc1);
            acc0 = fmaf(w6, bf_lo(u6), acc0); acc1 = fmaf(w6, bf_hi(u6), acc1);
            acc0 = fmaf(w7, bf_lo(u7), acc0); acc1 = fmaf(w7, bf_hi(u7), acc1);
        }
        for (; e < end; ++e) {
            const unsigned p = srcw[e];
            const unsigned u = hu[((p >> 15) << 6) | lane];
            const float w = (float)(p & 0x7FFFu) * INV_WQ;
            acc0 = fmaf(w, bf_lo(u), acc0);
            acc1 = fmaf(w, bf_hi(u), acc1);
        }
        *(float2*)&sagg[wave][2 * lane] =
            make_float2(fmaxf(acc0, 0.f), fmaxf(acc1, 0.f));

        // z2 = agg @ W2 + b2: fp32 quads, pure-FMA epilogue
        float acc = bias;
        #pragma unroll 4
        for (int k4 = 0; k4 < 32; ++k4) {
            const float4 w = sW2q[k4 * 64 + lane];                   // b128 seq
            const float4 a = *(const float4*)(&sagg[wave][4 * k4]);  // broadcast
            acc = fmaf(a.x, w.x, acc);
            acc = fmaf(a.y, w.y, acc);
            acc = fmaf(a.z, w.z, acc);
            acc = fmaf(a.w, w.w, acc);
        }
        z2h[(size_t)row * NC + lane] = f2bf(acc);
    }
}

// ---------------------------------------------------------------------------
// Gather-SPMM D=64 (bf16 table) + fused softmax, x8 edge unroll
// ---------------------------------------------------------------------------
__global__ __launch_bounds__(256, 8) void k_spmm2_softmax(
    const unsigned short* __restrict__ z2h, const int* __restrict__ rowptr,
    const unsigned* __restrict__ srcw, float* __restrict__ out)
{
    const int row = blockIdx.x * 4 + (threadIdx.x >> 6);
    if (row >= NN) return;
    const int lane = threadIdx.x & 63;
    const int start = rowptr[row], end = rowptr[row + 1];
    float acc = 0.f;
    int e = start;
    for (; e + 8 <= end; e += 8) {
        const unsigned p0 = srcw[e + 0], p1 = srcw[e + 1];
        const unsigned p2 = srcw[e + 2], p3 = srcw[e + 3];
        const unsigned p4 = srcw[e + 4], p5 = srcw[e + 5];
        const unsigned p6 = srcw[e + 6], p7 = srcw[e + 7];
        const unsigned short t0 = z2h[((p0 >> 15) << 6) | lane];
        const unsigned short t1 = z2h[((p1 >> 15) << 6) | lane];
        const unsigned short t2 = z2h[((p2 >> 15) << 6) | lane];
        const unsigned short t3 = z2h[((p3 >> 15) << 6) | lane];
        const unsigned short t4 = z2h[((p4 >> 15) << 6) | lane];
        const unsigned short t5 = z2h[((p5 >> 15) << 6) | lane];
        const unsigned short t6 = z2h[((p6 >> 15) << 6) | lane];
        const unsigned short t7 = z2h[((p7 >> 15) << 6) | lane];
        acc = fmaf((float)(p0 & 0x7FFFu) * INV_WQ,
                   __uint_as_float((unsigned)t0 << 16), acc);
        acc = fmaf((float)(p1 & 0x7FFFu) * INV_WQ,
                   __uint_as_float((unsigned)t1 << 16), acc);
        acc = fmaf((float)(p2 & 0x7FFFu) * INV_WQ,
                   __uint_as_float((unsigned)t2 << 16), acc);
        acc = fmaf((float)(p3 & 0x7FFFu) * INV_WQ,
                   __uint_as_float((unsigned)t3 << 16), acc);
        acc = fmaf((float)(p4 & 0x7FFFu) * INV_WQ,
                   __uint_as_float((unsigned)t4 << 16), acc);
        acc = fmaf((float)(p5 & 0x7FFFu) * INV_WQ,
                   __uint_as_float((unsigned)t5 << 16), acc);
        acc = fmaf((float)(p6 & 0x7FFFu) * INV_WQ,
                   __uint_as_float((unsigned)t6 << 16), acc);
        acc = fmaf((float)(p7 & 0x7FFFu) * INV_WQ,
                   __uint_as_float((unsigned)t7 << 16), acc);
    }
    for (; e < end; ++e) {
        const unsigned p = srcw[e];
        const float v = __uint_as_float(
            (unsigned)z2h[((p >> 15) << 6) | lane] << 16);
        acc = fmaf((float)(p & 0x7FFFu) * INV_WQ, v, acc);
    }
    float m = acc;
    #pragma unroll
    for (int off = 32; off; off >>= 1) m = fmaxf(m, __shfl_xor(m, off));
    const float ex = __expf(acc - m);
    float s = ex;
    #pragma unroll
    for (int off = 32; off; off >>= 1) s += __shfl_xor(s, off);
    out[(size_t)row * NC + lane] = ex / s;
}

// ---------------------------------------------------------------------------
extern "C" void kernel_launch(void* const* d_in, const int* in_sizes, int n_in,
                              void* d_out, int out_size, void* d_ws,
                              size_t ws_size, hipStream_t stream)
{
    const float* x  = (const float*)d_in[0];
    const int* src  = (const int*)d_in[1];
    const int* dst  = (const int*)d_in[2];
    const float* ew = (const float*)d_in[3];
    const float* W1 = (const float*)d_in[4];
    const float* b1 = (const float*)d_in[5];
    const float* W2 = (const float*)d_in[6];
    const float* b2 = (const float*)d_in[7];
    float* out = (float*)d_out;

    char* base = (char*)d_ws;
    unsigned short* z1h = (unsigned short*)base;  base += (size_t)NN * DH * 2;
    unsigned short* z2h = (unsigned short*)base;  base += (size_t)NN * NC * 2;
    unsigned* srcw = (unsigned*)base;             base += (size_t)NE * 4;
    int* rank   = (int*)base;                     base += (size_t)NE * 4;
    int* rowptr = (int*)base;                     base += ((size_t)NN + 2) * 4;
    int* cnt    = (int*)base;                     base += (size_t)NN * 4;
    int* bsum   = (int*)base;                     base += 512 * 4;
    float4* W2q = (float4*)base;                  base += 2048 * 16;

    hipMemsetAsync(cnt, 0, (size_t)NN * 4, stream);

    k_packW2q<<<8, 256, 0, stream>>>(W2, W2q);
    k_norm_gemm1<<<1024, 512, 0, stream>>>(x, W1, b1, z1h);

    k_hist   <<<2048, 256, 0, stream>>>(dst, cnt, rank);
    k_scanA  <<<NB, 256, 0, stream>>>(cnt, rowptr, bsum);
    k_scanB  <<<1, 512, 0, stream>>>(bsum);
    k_scanC  <<<NB, 256, 0, stream>>>(rowptr, bsum);
    k_scatter<<<2048, 256, 0, stream>>>(src, dst, ew, rowptr, rank, srcw);

    k_spmm1_gemm2   <<<2048, 512, 0, stream>>>(z1h, rowptr, srcw, W2q, b2, z2h);
    k_spmm2_softmax <<<(NN + 3) / 4, 256, 0, stream>>>(z2h, rowptr, srcw, out);
}